// Round 7
// baseline (52.030 us; speedup 1.0000x reference)
//
#include <hip/hip_runtime.h>

// WaveletEncoder: 2-level DWT detail-band means + MLP, collapsed analytically.
// All outputs depend on x only via per-(b,c) 4x4 parity sums
//   U[m][n] = sum_{h%4==m, w%4==n} x[b,c,h,w].
// scale-0 band mean = (1/4096) * sum_pq w_k0[p,q] * S[p][q]
// scale-1 band mean = (1/1024) * sum_rs w_k1[r,s] * T[r][s],
//   T[r][s] = sum_pq w_ll0[p,q] * U[2r+p][2s+q]
//
// ROUND 6 FIX: __builtin_nontemporal_load rejects HIP_vector_type (float4 is
// a class). Use a clang ext_vector_type(4) alias instead — same layout, and
// the builtin accepts it (emits global_load_dwordx4 with nt).

#define NB    16
#define NC    256
#define IMGW  128
#define IMGE  (IMGW * IMGW)
#define AGGD  1536   // 6 * 256
#define H1D   256    // 2 * DF, DF = 128
#define OUTD  128    // DF
#define AGG_BYTES (NB * AGGD * sizeof(float))          // 98304
#define HS_BYTES  (NB * H1D * sizeof(float))           // 16384
#define WS_NEEDED (AGG_BYTES + HS_BYTES)               // 114688

typedef float vfloat4 __attribute__((ext_vector_type(4)));

// ---- per-channel analytic combine: U[16] (m*4+n) -> 6 agg entries ---------
__device__ __forceinline__ void combine_and_store(
    const float* U, int c,
    const float* __restrict__ w_ll0, const float* __restrict__ w_lh0,
    const float* __restrict__ w_hl0, const float* __restrict__ w_hh0,
    const float* __restrict__ w_lh1, const float* __restrict__ w_hl1,
    const float* __restrict__ w_hh1,
    float* rowp /* agg row base (1536 floats), global or LDS */)
{
    const float S00 = U[0]  + U[2]  + U[8]  + U[10];
    const float S01 = U[1]  + U[3]  + U[9]  + U[11];
    const float S10 = U[4]  + U[6]  + U[12] + U[14];
    const float S11 = U[5]  + U[7]  + U[13] + U[15];

    const float l00 = w_ll0[c * 4 + 0], l01 = w_ll0[c * 4 + 1];
    const float l10 = w_ll0[c * 4 + 2], l11 = w_ll0[c * 4 + 3];
    const float T00 = l00 * U[0]  + l01 * U[1]  + l10 * U[4]  + l11 * U[5];
    const float T01 = l00 * U[2]  + l01 * U[3]  + l10 * U[6]  + l11 * U[7];
    const float T10 = l00 * U[8]  + l01 * U[9]  + l10 * U[12] + l11 * U[13];
    const float T11 = l00 * U[10] + l01 * U[11] + l10 * U[14] + l11 * U[15];

    const float inv0 = 1.0f / 4096.0f;
    const float inv1 = 1.0f / 1024.0f;
    const float* wlh0 = w_lh0 + c * 4;
    const float* whl0 = w_hl0 + c * 4;
    const float* whh0 = w_hh0 + c * 4;
    const float* wlh1 = w_lh1 + c * 4;
    const float* whl1 = w_hl1 + c * 4;
    const float* whh1 = w_hh1 + c * 4;

    rowp[0 * NC + c] = inv0 * (wlh0[0] * S00 + wlh0[1] * S01 + wlh0[2] * S10 + wlh0[3] * S11);
    rowp[1 * NC + c] = inv0 * (whl0[0] * S00 + whl0[1] * S01 + whl0[2] * S10 + whl0[3] * S11);
    rowp[2 * NC + c] = inv0 * (whh0[0] * S00 + whh0[1] * S01 + whh0[2] * S10 + whh0[3] * S11);
    rowp[3 * NC + c] = inv1 * (wlh1[0] * T00 + wlh1[1] * T01 + wlh1[2] * T10 + wlh1[3] * T11);
    rowp[4 * NC + c] = inv1 * (whl1[0] * T00 + whl1[1] * T01 + whl1[2] * T10 + whl1[3] * T11);
    rowp[5 * NC + c] = inv1 * (whh1[0] * T00 + whh1[1] * T01 + whh1[2] * T10 + whh1[3] * T11);
}

// ======================= stage 1: x -> agg (16,1536) =======================
__global__ __launch_bounds__(256) void dwt_parity_reduce(
    const float* __restrict__ x,
    const float* __restrict__ w_ll0, const float* __restrict__ w_lh0,
    const float* __restrict__ w_hl0, const float* __restrict__ w_hh0,
    const float* __restrict__ w_lh1, const float* __restrict__ w_hl1,
    const float* __restrict__ w_hh1,
    float* __restrict__ agg)
{
    const int bc = blockIdx.x;          // b*256 + c, grid = 4096
    const int b  = bc >> 8;
    const int c  = bc & 255;
    const int t  = threadIdx.x;
    const int col4 = t & 31;            // float4 index within a row
    const int row0 = t >> 5;            // 0..7; rows row0+8k -> parity m = row0&3
    const float* img = x + (size_t)bc * IMGE;

    float a0 = 0.f, a1 = 0.f, a2 = 0.f, a3 = 0.f;
    #pragma unroll
    for (int it = 0; it < 16; ++it) {
        // x is read exactly once across the whole problem: nontemporal load
        // so the 256 MB stream doesn't churn L2/LLC.
        const vfloat4 v = __builtin_nontemporal_load(
            reinterpret_cast<const vfloat4*>(img + (row0 + (it << 3)) * IMGW + col4 * 4));
        a0 += v.x; a1 += v.y; a2 += v.z; a3 += v.w;   // n = component index
    }
    #pragma unroll
    for (int mask = 16; mask >= 1; mask >>= 1) {
        a0 += __shfl_xor(a0, mask, 32);
        a1 += __shfl_xor(a1, mask, 32);
        a2 += __shfl_xor(a2, mask, 32);
        a3 += __shfl_xor(a3, mask, 32);
    }
    __shared__ float red[8][4];
    if ((t & 31) == 0) {
        red[row0][0] = a0; red[row0][1] = a1; red[row0][2] = a2; red[row0][3] = a3;
    }
    __syncthreads();
    if (t == 0) {
        float U[16];
        #pragma unroll
        for (int m = 0; m < 4; ++m)
            #pragma unroll
            for (int n = 0; n < 4; ++n)
                U[m * 4 + n] = red[m][n] + red[m + 4][n];
        combine_and_store(U, c, w_ll0, w_lh0, w_hl0, w_hh0,
                          w_lh1, w_hl1, w_hh1, agg + (size_t)b * AGGD);
    }
}

// ============ stage 2a: hs = relu(agg @ W1.T + b1), wave per dot ===========
// grid = 1024 blocks x 256 thr; wave (b, j): j = (bid&63)*4 + wv
__global__ __launch_bounds__(256) void mlp1_kernel(
    const float* __restrict__ agg, const float* __restrict__ W1,
    const float* __restrict__ b1, float* __restrict__ hs)
{
    const int bid  = blockIdx.x;
    const int b    = bid >> 6;          // 0..15
    const int jg   = bid & 63;
    const int lane = threadIdx.x & 63;
    const int j    = jg * 4 + (threadIdx.x >> 6);   // 0..255

    const float* arow = agg + (size_t)b * AGGD;
    const float* wrow = W1  + (size_t)j * AGGD;
    float p = 0.f;
    #pragma unroll
    for (int i = 0; i < 6; ++i) {
        const int k = i * 256 + lane * 4;           // 1536 = 6 * 256
        const float4 a = *reinterpret_cast<const float4*>(arow + k);
        const float4 w = *reinterpret_cast<const float4*>(wrow + k);
        p += a.x * w.x + a.y * w.y + a.z * w.z + a.w * w.w;
    }
    #pragma unroll
    for (int mask = 32; mask >= 1; mask >>= 1) p += __shfl_xor(p, mask, 64);
    if (lane == 0) hs[b * H1D + j] = fmaxf(p + b1[j], 0.f);
}

// ============ stage 2b: out = hs @ W2.T + b2, wave per dot =================
// grid = 512 blocks x 256 thr; wave (b, o): o = (bid&31)*4 + wv
__global__ __launch_bounds__(256) void mlp2_kernel(
    const float* __restrict__ hs, const float* __restrict__ W2,
    const float* __restrict__ b2, float* __restrict__ out)
{
    const int bid  = blockIdx.x;
    const int b    = bid >> 5;          // 0..15
    const int og   = bid & 31;
    const int lane = threadIdx.x & 63;
    const int o    = og * 4 + (threadIdx.x >> 6);   // 0..127

    const float4 h = *reinterpret_cast<const float4*>(hs + (size_t)b * H1D + lane * 4);
    const float4 w = *reinterpret_cast<const float4*>(W2 + (size_t)o * H1D + lane * 4);
    float p = h.x * w.x + h.y * w.y + h.z * w.z + h.w * w.w;
    #pragma unroll
    for (int mask = 32; mask >= 1; mask >>= 1) p += __shfl_xor(p, mask, 64);
    if (lane == 0) out[b * OUTD + o] = p + b2[o];
}

// ========== legacy single-block-per-batch MLP (small-ws fallback) ==========
__global__ __launch_bounds__(256) void mlp_kernel(
    const float* __restrict__ agg,
    const float* __restrict__ W1, const float* __restrict__ b1,
    const float* __restrict__ W2, const float* __restrict__ b2,
    float* __restrict__ out)
{
    const int b    = blockIdx.x;
    const int t    = threadIdx.x;
    const int lane = t & 63;
    const int wv   = t >> 6;

    __shared__ float aggs[AGGD];
    __shared__ float hs[H1D];

    for (int i = t; i < AGGD; i += 256) aggs[i] = agg[(size_t)b * AGGD + i];
    __syncthreads();

    for (int j = wv; j < H1D; j += 4) {
        const float* wrow = W1 + (size_t)j * AGGD;
        float p = 0.f;
        #pragma unroll 4
        for (int k = lane; k < AGGD; k += 64) p += aggs[k] * wrow[k];
        #pragma unroll
        for (int mask = 32; mask >= 1; mask >>= 1) p += __shfl_xor(p, mask, 64);
        if (lane == 0) hs[j] = fmaxf(p + b1[j], 0.f);
    }
    __syncthreads();

    for (int o = wv; o < OUTD; o += 4) {
        const float* wrow = W2 + (size_t)o * H1D;
        float p = 0.f;
        #pragma unroll
        for (int k = lane; k < H1D; k += 64) p += hs[k] * wrow[k];
        #pragma unroll
        for (int mask = 32; mask >= 1; mask >>= 1) p += __shfl_xor(p, mask, 64);
        if (lane == 0) out[(size_t)b * OUTD + o] = p + b2[o];
    }
}

// ============== fallback (no global scratch): 16 blocks x 256 ==============
__global__ __launch_bounds__(256) void fused_fallback(
    const float* __restrict__ x,
    const float* __restrict__ w_ll0, const float* __restrict__ w_lh0,
    const float* __restrict__ w_hl0, const float* __restrict__ w_hh0,
    const float* __restrict__ w_lh1, const float* __restrict__ w_hl1,
    const float* __restrict__ w_hh1,
    const float* __restrict__ W1, const float* __restrict__ b1,
    const float* __restrict__ W2, const float* __restrict__ b2,
    float* __restrict__ out)
{
    const int b    = blockIdx.x;
    const int t    = threadIdx.x;
    const int lane = t & 63;
    const int wv   = t >> 6;
    const int col4 = t & 31;
    const int row0 = t >> 5;

    __shared__ float red[8][4];
    __shared__ float aggs[AGGD];
    __shared__ float hs[H1D];

    for (int c = 0; c < NC; ++c) {
        const float* img = x + ((size_t)b * NC + c) * IMGE;
        float a0 = 0.f, a1 = 0.f, a2 = 0.f, a3 = 0.f;
        #pragma unroll
        for (int it = 0; it < 16; ++it) {
            const float4 v = *reinterpret_cast<const float4*>(
                img + (row0 + (it << 3)) * IMGW + col4 * 4);
            a0 += v.x; a1 += v.y; a2 += v.z; a3 += v.w;
        }
        #pragma unroll
        for (int mask = 16; mask >= 1; mask >>= 1) {
            a0 += __shfl_xor(a0, mask, 32);
            a1 += __shfl_xor(a1, mask, 32);
            a2 += __shfl_xor(a2, mask, 32);
            a3 += __shfl_xor(a3, mask, 32);
        }
        if ((t & 31) == 0) {
            red[row0][0] = a0; red[row0][1] = a1; red[row0][2] = a2; red[row0][3] = a3;
        }
        __syncthreads();
        if (t == 0) {
            float U[16];
            #pragma unroll
            for (int m = 0; m < 4; ++m)
                #pragma unroll
                for (int n = 0; n < 4; ++n)
                    U[m * 4 + n] = red[m][n] + red[m + 4][n];
            combine_and_store(U, c, w_ll0, w_lh0, w_hl0, w_hh0,
                              w_lh1, w_hl1, w_hh1, aggs);
        }
        __syncthreads();
    }

    for (int j = wv; j < H1D; j += 4) {
        const float* wrow = W1 + (size_t)j * AGGD;
        float p = 0.f;
        #pragma unroll 4
        for (int k = lane; k < AGGD; k += 64) p += aggs[k] * wrow[k];
        #pragma unroll
        for (int mask = 32; mask >= 1; mask >>= 1) p += __shfl_xor(p, mask, 64);
        if (lane == 0) hs[j] = fmaxf(p + b1[j], 0.f);
    }
    __syncthreads();

    for (int o = wv; o < OUTD; o += 4) {
        const float* wrow = W2 + (size_t)o * H1D;
        float p = 0.f;
        #pragma unroll
        for (int k = lane; k < H1D; k += 64) p += hs[k] * wrow[k];
        #pragma unroll
        for (int mask = 32; mask >= 1; mask >>= 1) p += __shfl_xor(p, mask, 64);
        if (lane == 0) out[(size_t)b * OUTD + o] = p + b2[o];
    }
}

// ---- diagnostic sentinel ---------------------------------------------------
__global__ void write_sentinel(float* out, int n, float code)
{
    const int i = blockIdx.x * blockDim.x + threadIdx.x;
    if (i < n) out[i] = (i == 0) ? code : 0.f;
}

extern "C" void kernel_launch(void* const* d_in, const int* in_sizes, int n_in,
                              void* d_out, int out_size, void* d_ws, size_t ws_size,
                              hipStream_t stream) {
    float* out = (float*)d_out;
    const int sent_grid = (out_size + 255) / 256;

    if (n_in != 13) {
        write_sentinel<<<sent_grid, 256, 0, stream>>>(out, out_size, 1000.0f);
        return;
    }
    static const int expected[13] = {
        NB * NC * IMGE,
        1024, 1024, 1024, 1024,
        1024, 1024, 1024, 1024,
        H1D * AGGD, H1D, OUTD * H1D, OUTD
    };
    for (int i = 0; i < 13; ++i) {
        if (in_sizes[i] != expected[i]) {
            write_sentinel<<<sent_grid, 256, 0, stream>>>(out, out_size,
                                                          2000.0f + (float)i);
            return;
        }
    }
    if (out_size != NB * OUTD) {
        write_sentinel<<<sent_grid, 256, 0, stream>>>(out, out_size, 3000.0f);
        return;
    }

    const float* x     = (const float*)d_in[0];
    const float* w_ll0 = (const float*)d_in[1];
    const float* w_lh0 = (const float*)d_in[2];
    const float* w_hl0 = (const float*)d_in[3];
    const float* w_hh0 = (const float*)d_in[4];
    // d_in[5] = w_ll1, unused (ll1 feeds no output band)
    const float* w_lh1 = (const float*)d_in[6];
    const float* w_hl1 = (const float*)d_in[7];
    const float* w_hh1 = (const float*)d_in[8];
    const float* W1    = (const float*)d_in[9];
    const float* b1    = (const float*)d_in[10];
    const float* W2    = (const float*)d_in[11];
    const float* b2    = (const float*)d_in[12];

    if (d_ws != nullptr && ws_size >= WS_NEEDED) {
        float* agg = (float*)d_ws;                         // (16,1536)
        float* hs  = (float*)((char*)d_ws + AGG_BYTES);    // (16,256)
        dwt_parity_reduce<<<NB * NC, 256, 0, stream>>>(
            x, w_ll0, w_lh0, w_hl0, w_hh0, w_lh1, w_hl1, w_hh1, agg);
        mlp1_kernel<<<1024, 256, 0, stream>>>(agg, W1, b1, hs);
        mlp2_kernel<<<512, 256, 0, stream>>>(hs, W2, b2, out);
    } else if (d_ws != nullptr && ws_size >= AGG_BYTES) {
        float* agg = (float*)d_ws;
        dwt_parity_reduce<<<NB * NC, 256, 0, stream>>>(
            x, w_ll0, w_lh0, w_hl0, w_hh0, w_lh1, w_hl1, w_hh1, agg);
        mlp_kernel<<<NB, 256, 0, stream>>>(agg, W1, b1, W2, b2, out);
    } else {
        fused_fallback<<<NB, 256, 0, stream>>>(
            x, w_ll0, w_lh0, w_hl0, w_hh0, w_lh1, w_hl1, w_hh1,
            W1, b1, W2, b2, out);
    }
}

// Round 8
// 49.798 us; speedup vs baseline: 1.0448x; 1.0448x over previous
//
#include <hip/hip_runtime.h>

// WaveletEncoder: 2-level DWT detail-band means + MLP, collapsed analytically.
// All outputs depend on x only via per-(b,c) 4x4 parity sums
//   U[m][n] = sum_{h%4==m, w%4==n} x[b,c,h,w].
// scale-0 band mean = (1/4096) * sum_pq w_k0[p,q] * S[p][q]
// scale-1 band mean = (1/1024) * sum_rs w_k1[r,s] * T[r][s],
//   T[r][s] = sum_pq w_ll0[p,q] * U[2r+p][2s+q]
//
// ROUND 7: revert round-5/6 nontemporal-load experiment (A/B: plain 50.2 us
// vs nt 52.0 us — nt regressed ~3.6%; L2/MALL handles the read-once stream
// fine). This is the round-4 kernel: composed roofline = 268 MB stream
// (42.6 us at 6.3 TB/s) + ~7 us serial MLP tail = ~50 us, measured 50.2.

#define NB    16
#define NC    256
#define IMGW  128
#define IMGE  (IMGW * IMGW)
#define AGGD  1536   // 6 * 256
#define H1D   256    // 2 * DF, DF = 128
#define OUTD  128    // DF
#define AGG_BYTES (NB * AGGD * sizeof(float))          // 98304
#define HS_BYTES  (NB * H1D * sizeof(float))           // 16384
#define WS_NEEDED (AGG_BYTES + HS_BYTES)               // 114688

// ---- per-channel analytic combine: U[16] (m*4+n) -> 6 agg entries ---------
__device__ __forceinline__ void combine_and_store(
    const float* U, int c,
    const float* __restrict__ w_ll0, const float* __restrict__ w_lh0,
    const float* __restrict__ w_hl0, const float* __restrict__ w_hh0,
    const float* __restrict__ w_lh1, const float* __restrict__ w_hl1,
    const float* __restrict__ w_hh1,
    float* rowp /* agg row base (1536 floats), global or LDS */)
{
    const float S00 = U[0]  + U[2]  + U[8]  + U[10];
    const float S01 = U[1]  + U[3]  + U[9]  + U[11];
    const float S10 = U[4]  + U[6]  + U[12] + U[14];
    const float S11 = U[5]  + U[7]  + U[13] + U[15];

    const float l00 = w_ll0[c * 4 + 0], l01 = w_ll0[c * 4 + 1];
    const float l10 = w_ll0[c * 4 + 2], l11 = w_ll0[c * 4 + 3];
    const float T00 = l00 * U[0]  + l01 * U[1]  + l10 * U[4]  + l11 * U[5];
    const float T01 = l00 * U[2]  + l01 * U[3]  + l10 * U[6]  + l11 * U[7];
    const float T10 = l00 * U[8]  + l01 * U[9]  + l10 * U[12] + l11 * U[13];
    const float T11 = l00 * U[10] + l01 * U[11] + l10 * U[14] + l11 * U[15];

    const float inv0 = 1.0f / 4096.0f;
    const float inv1 = 1.0f / 1024.0f;
    const float* wlh0 = w_lh0 + c * 4;
    const float* whl0 = w_hl0 + c * 4;
    const float* whh0 = w_hh0 + c * 4;
    const float* wlh1 = w_lh1 + c * 4;
    const float* whl1 = w_hl1 + c * 4;
    const float* whh1 = w_hh1 + c * 4;

    rowp[0 * NC + c] = inv0 * (wlh0[0] * S00 + wlh0[1] * S01 + wlh0[2] * S10 + wlh0[3] * S11);
    rowp[1 * NC + c] = inv0 * (whl0[0] * S00 + whl0[1] * S01 + whl0[2] * S10 + whl0[3] * S11);
    rowp[2 * NC + c] = inv0 * (whh0[0] * S00 + whh0[1] * S01 + whh0[2] * S10 + whh0[3] * S11);
    rowp[3 * NC + c] = inv1 * (wlh1[0] * T00 + wlh1[1] * T01 + wlh1[2] * T10 + wlh1[3] * T11);
    rowp[4 * NC + c] = inv1 * (whl1[0] * T00 + whl1[1] * T01 + whl1[2] * T10 + whl1[3] * T11);
    rowp[5 * NC + c] = inv1 * (whh1[0] * T00 + whh1[1] * T01 + whh1[2] * T10 + whh1[3] * T11);
}

// ======================= stage 1: x -> agg (16,1536) =======================
__global__ __launch_bounds__(256) void dwt_parity_reduce(
    const float* __restrict__ x,
    const float* __restrict__ w_ll0, const float* __restrict__ w_lh0,
    const float* __restrict__ w_hl0, const float* __restrict__ w_hh0,
    const float* __restrict__ w_lh1, const float* __restrict__ w_hl1,
    const float* __restrict__ w_hh1,
    float* __restrict__ agg)
{
    const int bc = blockIdx.x;          // b*256 + c, grid = 4096
    const int b  = bc >> 8;
    const int c  = bc & 255;
    const int t  = threadIdx.x;
    const int col4 = t & 31;            // float4 index within a row
    const int row0 = t >> 5;            // 0..7; rows row0+8k -> parity m = row0&3
    const float* img = x + (size_t)bc * IMGE;

    float a0 = 0.f, a1 = 0.f, a2 = 0.f, a3 = 0.f;
    #pragma unroll
    for (int it = 0; it < 16; ++it) {
        const float4 v = *reinterpret_cast<const float4*>(
            img + (row0 + (it << 3)) * IMGW + col4 * 4);
        a0 += v.x; a1 += v.y; a2 += v.z; a3 += v.w;   // n = component index
    }
    #pragma unroll
    for (int mask = 16; mask >= 1; mask >>= 1) {
        a0 += __shfl_xor(a0, mask, 32);
        a1 += __shfl_xor(a1, mask, 32);
        a2 += __shfl_xor(a2, mask, 32);
        a3 += __shfl_xor(a3, mask, 32);
    }
    __shared__ float red[8][4];
    if ((t & 31) == 0) {
        red[row0][0] = a0; red[row0][1] = a1; red[row0][2] = a2; red[row0][3] = a3;
    }
    __syncthreads();
    if (t == 0) {
        float U[16];
        #pragma unroll
        for (int m = 0; m < 4; ++m)
            #pragma unroll
            for (int n = 0; n < 4; ++n)
                U[m * 4 + n] = red[m][n] + red[m + 4][n];
        combine_and_store(U, c, w_ll0, w_lh0, w_hl0, w_hh0,
                          w_lh1, w_hl1, w_hh1, agg + (size_t)b * AGGD);
    }
}

// ============ stage 2a: hs = relu(agg @ W1.T + b1), wave per dot ===========
// grid = 1024 blocks x 256 thr; wave (b, j): j = (bid&63)*4 + wv
__global__ __launch_bounds__(256) void mlp1_kernel(
    const float* __restrict__ agg, const float* __restrict__ W1,
    const float* __restrict__ b1, float* __restrict__ hs)
{
    const int bid  = blockIdx.x;
    const int b    = bid >> 6;          // 0..15
    const int jg   = bid & 63;
    const int lane = threadIdx.x & 63;
    const int j    = jg * 4 + (threadIdx.x >> 6);   // 0..255

    const float* arow = agg + (size_t)b * AGGD;
    const float* wrow = W1  + (size_t)j * AGGD;
    float p = 0.f;
    #pragma unroll
    for (int i = 0; i < 6; ++i) {
        const int k = i * 256 + lane * 4;           // 1536 = 6 * 256
        const float4 a = *reinterpret_cast<const float4*>(arow + k);
        const float4 w = *reinterpret_cast<const float4*>(wrow + k);
        p += a.x * w.x + a.y * w.y + a.z * w.z + a.w * w.w;
    }
    #pragma unroll
    for (int mask = 32; mask >= 1; mask >>= 1) p += __shfl_xor(p, mask, 64);
    if (lane == 0) hs[b * H1D + j] = fmaxf(p + b1[j], 0.f);
}

// ============ stage 2b: out = hs @ W2.T + b2, wave per dot =================
// grid = 512 blocks x 256 thr; wave (b, o): o = (bid&31)*4 + wv
__global__ __launch_bounds__(256) void mlp2_kernel(
    const float* __restrict__ hs, const float* __restrict__ W2,
    const float* __restrict__ b2, float* __restrict__ out)
{
    const int bid  = blockIdx.x;
    const int b    = bid >> 5;          // 0..15
    const int og   = bid & 31;
    const int lane = threadIdx.x & 63;
    const int o    = og * 4 + (threadIdx.x >> 6);   // 0..127

    const float4 h = *reinterpret_cast<const float4*>(hs + (size_t)b * H1D + lane * 4);
    const float4 w = *reinterpret_cast<const float4*>(W2 + (size_t)o * H1D + lane * 4);
    float p = h.x * w.x + h.y * w.y + h.z * w.z + h.w * w.w;
    #pragma unroll
    for (int mask = 32; mask >= 1; mask >>= 1) p += __shfl_xor(p, mask, 64);
    if (lane == 0) out[b * OUTD + o] = p + b2[o];
}

// ========== legacy single-block-per-batch MLP (small-ws fallback) ==========
__global__ __launch_bounds__(256) void mlp_kernel(
    const float* __restrict__ agg,
    const float* __restrict__ W1, const float* __restrict__ b1,
    const float* __restrict__ W2, const float* __restrict__ b2,
    float* __restrict__ out)
{
    const int b    = blockIdx.x;
    const int t    = threadIdx.x;
    const int lane = t & 63;
    const int wv   = t >> 6;

    __shared__ float aggs[AGGD];
    __shared__ float hs[H1D];

    for (int i = t; i < AGGD; i += 256) aggs[i] = agg[(size_t)b * AGGD + i];
    __syncthreads();

    for (int j = wv; j < H1D; j += 4) {
        const float* wrow = W1 + (size_t)j * AGGD;
        float p = 0.f;
        #pragma unroll 4
        for (int k = lane; k < AGGD; k += 64) p += aggs[k] * wrow[k];
        #pragma unroll
        for (int mask = 32; mask >= 1; mask >>= 1) p += __shfl_xor(p, mask, 64);
        if (lane == 0) hs[j] = fmaxf(p + b1[j], 0.f);
    }
    __syncthreads();

    for (int o = wv; o < OUTD; o += 4) {
        const float* wrow = W2 + (size_t)o * H1D;
        float p = 0.f;
        #pragma unroll
        for (int k = lane; k < H1D; k += 64) p += hs[k] * wrow[k];
        #pragma unroll
        for (int mask = 32; mask >= 1; mask >>= 1) p += __shfl_xor(p, mask, 64);
        if (lane == 0) out[(size_t)b * OUTD + o] = p + b2[o];
    }
}

// ============== fallback (no global scratch): 16 blocks x 256 ==============
__global__ __launch_bounds__(256) void fused_fallback(
    const float* __restrict__ x,
    const float* __restrict__ w_ll0, const float* __restrict__ w_lh0,
    const float* __restrict__ w_hl0, const float* __restrict__ w_hh0,
    const float* __restrict__ w_lh1, const float* __restrict__ w_hl1,
    const float* __restrict__ w_hh1,
    const float* __restrict__ W1, const float* __restrict__ b1,
    const float* __restrict__ W2, const float* __restrict__ b2,
    float* __restrict__ out)
{
    const int b    = blockIdx.x;
    const int t    = threadIdx.x;
    const int lane = t & 63;
    const int wv   = t >> 6;
    const int col4 = t & 31;
    const int row0 = t >> 5;

    __shared__ float red[8][4];
    __shared__ float aggs[AGGD];
    __shared__ float hs[H1D];

    for (int c = 0; c < NC; ++c) {
        const float* img = x + ((size_t)b * NC + c) * IMGE;
        float a0 = 0.f, a1 = 0.f, a2 = 0.f, a3 = 0.f;
        #pragma unroll
        for (int it = 0; it < 16; ++it) {
            const float4 v = *reinterpret_cast<const float4*>(
                img + (row0 + (it << 3)) * IMGW + col4 * 4);
            a0 += v.x; a1 += v.y; a2 += v.z; a3 += v.w;
        }
        #pragma unroll
        for (int mask = 16; mask >= 1; mask >>= 1) {
            a0 += __shfl_xor(a0, mask, 32);
            a1 += __shfl_xor(a1, mask, 32);
            a2 += __shfl_xor(a2, mask, 32);
            a3 += __shfl_xor(a3, mask, 32);
        }
        if ((t & 31) == 0) {
            red[row0][0] = a0; red[row0][1] = a1; red[row0][2] = a2; red[row0][3] = a3;
        }
        __syncthreads();
        if (t == 0) {
            float U[16];
            #pragma unroll
            for (int m = 0; m < 4; ++m)
                #pragma unroll
                for (int n = 0; n < 4; ++n)
                    U[m * 4 + n] = red[m][n] + red[m + 4][n];
            combine_and_store(U, c, w_ll0, w_lh0, w_hl0, w_hh0,
                              w_lh1, w_hl1, w_hh1, aggs);
        }
        __syncthreads();
    }

    for (int j = wv; j < H1D; j += 4) {
        const float* wrow = W1 + (size_t)j * AGGD;
        float p = 0.f;
        #pragma unroll 4
        for (int k = lane; k < AGGD; k += 64) p += aggs[k] * wrow[k];
        #pragma unroll
        for (int mask = 32; mask >= 1; mask >>= 1) p += __shfl_xor(p, mask, 64);
        if (lane == 0) hs[j] = fmaxf(p + b1[j], 0.f);
    }
    __syncthreads();

    for (int o = wv; o < OUTD; o += 4) {
        const float* wrow = W2 + (size_t)o * H1D;
        float p = 0.f;
        #pragma unroll
        for (int k = lane; k < H1D; k += 64) p += hs[k] * wrow[k];
        #pragma unroll
        for (int mask = 32; mask >= 1; mask >>= 1) p += __shfl_xor(p, mask, 64);
        if (lane == 0) out[(size_t)b * OUTD + o] = p + b2[o];
    }
}

// ---- diagnostic sentinel ---------------------------------------------------
__global__ void write_sentinel(float* out, int n, float code)
{
    const int i = blockIdx.x * blockDim.x + threadIdx.x;
    if (i < n) out[i] = (i == 0) ? code : 0.f;
}

extern "C" void kernel_launch(void* const* d_in, const int* in_sizes, int n_in,
                              void* d_out, int out_size, void* d_ws, size_t ws_size,
                              hipStream_t stream) {
    float* out = (float*)d_out;
    const int sent_grid = (out_size + 255) / 256;

    if (n_in != 13) {
        write_sentinel<<<sent_grid, 256, 0, stream>>>(out, out_size, 1000.0f);
        return;
    }
    static const int expected[13] = {
        NB * NC * IMGE,
        1024, 1024, 1024, 1024,
        1024, 1024, 1024, 1024,
        H1D * AGGD, H1D, OUTD * H1D, OUTD
    };
    for (int i = 0; i < 13; ++i) {
        if (in_sizes[i] != expected[i]) {
            write_sentinel<<<sent_grid, 256, 0, stream>>>(out, out_size,
                                                          2000.0f + (float)i);
            return;
        }
    }
    if (out_size != NB * OUTD) {
        write_sentinel<<<sent_grid, 256, 0, stream>>>(out, out_size, 3000.0f);
        return;
    }

    const float* x     = (const float*)d_in[0];
    const float* w_ll0 = (const float*)d_in[1];
    const float* w_lh0 = (const float*)d_in[2];
    const float* w_hl0 = (const float*)d_in[3];
    const float* w_hh0 = (const float*)d_in[4];
    // d_in[5] = w_ll1, unused (ll1 feeds no output band)
    const float* w_lh1 = (const float*)d_in[6];
    const float* w_hl1 = (const float*)d_in[7];
    const float* w_hh1 = (const float*)d_in[8];
    const float* W1    = (const float*)d_in[9];
    const float* b1    = (const float*)d_in[10];
    const float* W2    = (const float*)d_in[11];
    const float* b2    = (const float*)d_in[12];

    if (d_ws != nullptr && ws_size >= WS_NEEDED) {
        float* agg = (float*)d_ws;                         // (16,1536)
        float* hs  = (float*)((char*)d_ws + AGG_BYTES);    // (16,256)
        dwt_parity_reduce<<<NB * NC, 256, 0, stream>>>(
            x, w_ll0, w_lh0, w_hl0, w_hh0, w_lh1, w_hl1, w_hh1, agg);
        mlp1_kernel<<<1024, 256, 0, stream>>>(agg, W1, b1, hs);
        mlp2_kernel<<<512, 256, 0, stream>>>(hs, W2, b2, out);
    } else if (d_ws != nullptr && ws_size >= AGG_BYTES) {
        float* agg = (float*)d_ws;
        dwt_parity_reduce<<<NB * NC, 256, 0, stream>>>(
            x, w_ll0, w_lh0, w_hl0, w_hh0, w_lh1, w_hl1, w_hh1, agg);
        mlp_kernel<<<NB, 256, 0, stream>>>(agg, W1, b1, W2, b2, out);
    } else {
        fused_fallback<<<NB, 256, 0, stream>>>(
            x, w_ll0, w_lh0, w_hl0, w_hh0, w_lh1, w_hl1, w_hh1,
            W1, b1, W2, b2, out);
    }
}